// Round 1
// baseline (7348.116 us; speedup 1.0000x reference)
//
#include <hip/hip_runtime.h>
#include <math.h>

#define NHEADS 6
#define HDIM 32
#define CCH 192
#define NT 32

__global__ __launch_bounds__(256, 2)
void vsa_kernel(const float* __restrict__ x,
                const float* __restrict__ qkv_w, const float* __restrict__ qkv_b,
                const float* __restrict__ proj_w, const float* __restrict__ proj_b,
                const float* __restrict__ rpb_table, const float* __restrict__ temperature,
                const float* __restrict__ qkvC_w, const float* __restrict__ dw_w,
                const float* __restrict__ projC_w, const float* __restrict__ projC_b,
                const float* __restrict__ gs_w1, const float* __restrict__ gs_b1,
                const float* __restrict__ bn_g, const float* __restrict__ bn_b,
                const float* __restrict__ bn_m, const float* __restrict__ bn_v,
                const float* __restrict__ gs_w2, const float* __restrict__ gs_b2,
                float* __restrict__ out)
{
    const int b = blockIdx.x;
    const int t = threadIdx.x;

    __shared__ float xs[NT][196];     // x tile, token-major, padded
    __shared__ float ao[NT][196];     // branch1 attn-out, then branch2 x2 (token-major)
    __shared__ float qb[3 * 32 * 36]; // per-head q/k/v (b1: [w][n][d]) or y/z (b2: [row][n])
    __shared__ float attnb[32][33];   // attention matrix (both branches)
    __shared__ float rl[105 * 6];     // rpb table
    __shared__ float y1n[32];
    __shared__ float aspl[32];

    const float* xb = x + (size_t)b * (NT * CCH);

    // ---- stage x tile (float4, coalesced) ----
    #pragma unroll
    for (int u = 0; u < 6; ++u) {
        int i = t + 256 * u;          // 1536 float4s
        int n = i / 48;
        int k = (i % 48) * 4;
        float4 v = *(const float4*)(xb + i * 4);
        *(float4*)&xs[n][k] = v;
    }
    for (int i = t; i < 105 * 6; i += 256) rl[i] = rpb_table[i];
    __syncthreads();

    // ---- spatial gate: pooled == 1/32 exactly (softmax rows sum to 1) ----
    if (t < 32) {
        float y1 = gs_b1[t];
        #pragma unroll
        for (int hh = 0; hh < 6; ++hh)
            y1 += gs_w1[t * 54 + hh * 9 + 4] * (1.0f / 32.0f);   // center tap only
        y1 = (y1 - bn_m[t]) * rsqrtf(bn_v[t] + 1e-5f) * bn_g[t] + bn_b[t];
        y1n[t] = y1;
    }
    __syncthreads();
    if (t < 32) {
        float y2 = gs_b2[t];
        #pragma unroll
        for (int c = 0; c < 32; ++c)
            y2 += gs_w2[t * 288 + c * 9 + 4] * y1n[c];
        aspl[t] = y2;
    }
    // aspl consumed only at the very end (many barriers in between)

    const int n_l = t & 31;
    const int jg = t >> 5;
    const float scale = 0.17677669529663687f;   // 32^-0.5

    // ================= branch 1: windowed spatial attention =================
    for (int h = 0; h < NHEADS; ++h) {
        { // qkv GEMM for head h: 32 tokens x 96 cols (q,k,v of this head)
            float acc[12];
            int wrow[12];
            #pragma unroll
            for (int r = 0; r < 12; ++r) {
                int jj = jg * 12 + r;
                int which = jj >> 5, d = jj & 31;
                wrow[r] = which * CCH + h * HDIM + d;
                acc[r] = qkv_b[wrow[r]];
            }
            for (int k4 = 0; k4 < 48; ++k4) {
                float4 xv = *(const float4*)&xs[n_l][k4 * 4];
                #pragma unroll
                for (int r = 0; r < 12; ++r) {
                    float4 wv = *(const float4*)(qkv_w + wrow[r] * CCH + k4 * 4);
                    acc[r] += xv.x * wv.x + xv.y * wv.y + xv.z * wv.z + xv.w * wv.w;
                }
            }
            #pragma unroll
            for (int r = 0; r < 12; ++r) {
                int jj = jg * 12 + r;
                int which = jj >> 5, d = jj & 31;
                float v = acc[r];
                if (which == 0) v *= scale;               // q * HD^-0.5 (post-bias)
                qb[which * 1152 + n_l * 36 + d] = v;      // [which][n][d]
            }
        }
        __syncthreads();
        { // attn = softmax(q k^T + rpb), rows owned by 8-lane groups
            const int nq = t >> 3, mg = t & 7;
            float4 qrow[8];
            #pragma unroll
            for (int k4 = 0; k4 < 8; ++k4)
                qrow[k4] = *(const float4*)&qb[nq * 36 + k4 * 4];
            float pv[4];
            float mx = -1e30f;
            #pragma unroll
            for (int r = 0; r < 4; ++r) {
                int m = mg + 8 * r;
                float s = 0.f;
                #pragma unroll
                for (int k4 = 0; k4 < 8; ++k4) {
                    float4 kv = *(const float4*)&qb[1152 + m * 36 + k4 * 4];
                    s += qrow[k4].x * kv.x + qrow[k4].y * kv.y
                       + qrow[k4].z * kv.z + qrow[k4].w * kv.w;
                }
                int dh = (nq >> 3) - (m >> 3) + 3;
                int dw = (nq & 7) - (m & 7) + 7;
                s += rl[(dh * 15 + dw) * 6 + h];
                pv[r] = s;
                mx = fmaxf(mx, s);
            }
            mx = fmaxf(mx, __shfl_xor(mx, 1));
            mx = fmaxf(mx, __shfl_xor(mx, 2));
            mx = fmaxf(mx, __shfl_xor(mx, 4));
            float sum = 0.f;
            #pragma unroll
            for (int r = 0; r < 4; ++r) { pv[r] = expf(pv[r] - mx); sum += pv[r]; }
            sum += __shfl_xor(sum, 1);
            sum += __shfl_xor(sum, 2);
            sum += __shfl_xor(sum, 4);
            float inv = 1.0f / sum;
            #pragma unroll
            for (int r = 0; r < 4; ++r) attnb[nq][mg + 8 * r] = pv[r] * inv;
        }
        __syncthreads();
        { // o = attn @ v -> ao[n][h*32+d]
            const int nq = t >> 3, dg = t & 7;
            float ox = 0, oy = 0, oz = 0, ow = 0;
            for (int m = 0; m < 32; ++m) {
                float a = attnb[nq][m];
                float4 vv = *(const float4*)&qb[2304 + m * 36 + dg * 4];
                ox += a * vv.x; oy += a * vv.y; oz += a * vv.z; ow += a * vv.w;
            }
            float4 o; o.x = ox; o.y = oy; o.z = oz; o.w = ow;
            *(float4*)&ao[nq][h * 32 + dg * 4] = o;
        }
        __syncthreads();
    }

    // ---- proj GEMM: acc1 (registers, 24 outputs per thread) ----
    const int np = t >> 3;   // token
    const int cq = t & 7;    // col-chunk
    float acc1[24];
    #pragma unroll
    for (int r = 0; r < 24; ++r) acc1[r] = proj_b[cq * 24 + r];
    for (int k4 = 0; k4 < 48; ++k4) {
        float4 xv = *(const float4*)&ao[np][k4 * 4];
        #pragma unroll
        for (int r = 0; r < 24; ++r) {
            float4 wv = *(const float4*)(proj_w + (cq * 24 + r) * CCH + k4 * 4);
            acc1[r] += xv.x * wv.x + xv.y * wv.y + xv.z * wv.z + xv.w * wv.w;
        }
    }

    // ================= branch 2: channel (MDTA) attention =================
    for (int h = 0; h < NHEADS; ++h) {
        { // pointwise 1x1 conv (GEMM), store channel-major: qb[row][n]
            float acc[12];
            int wrow[12];
            #pragma unroll
            for (int r = 0; r < 12; ++r) {
                int jj = jg * 12 + r;
                int which = jj >> 5, d = jj & 31;
                wrow[r] = which * CCH + h * HDIM + d;
                acc[r] = 0.f;
            }
            for (int k4 = 0; k4 < 48; ++k4) {
                float4 xv = *(const float4*)&xs[n_l][k4 * 4];
                #pragma unroll
                for (int r = 0; r < 12; ++r) {
                    float4 wv = *(const float4*)(qkvC_w + wrow[r] * CCH + k4 * 4);
                    acc[r] += xv.x * wv.x + xv.y * wv.y + xv.z * wv.z + xv.w * wv.w;
                }
            }
            #pragma unroll
            for (int r = 0; r < 12; ++r) {
                int jj = jg * 12 + r;
                int which = jj >> 5, d = jj & 31;
                qb[(which * 32 + d) * 36 + n_l] = acc[r];
            }
        }
        __syncthreads();
        { // depthwise 3x3 over the 4x8 window, in-place via registers
            const int nn = t & 31, rg = t >> 5;
            const int nh_ = nn >> 3, nw_ = nn & 7;
            float zreg[12];
            #pragma unroll
            for (int r = 0; r < 12; ++r) {
                int rr = rg + 8 * r;                 // 0..95
                int which = rr >> 5, d = rr & 31;
                int oc = which * CCH + h * HDIM + d;
                const float* wp = dw_w + oc * 9;
                float s = 0.f;
                #pragma unroll
                for (int dh2 = 0; dh2 < 3; ++dh2) {
                    int nh2 = nh_ + dh2 - 1;
                    if (nh2 < 0 || nh2 >= 4) continue;
                    #pragma unroll
                    for (int dw2 = 0; dw2 < 3; ++dw2) {
                        int nw2 = nw_ + dw2 - 1;
                        if (nw2 < 0 || nw2 >= 8) continue;
                        s += wp[dh2 * 3 + dw2] * qb[rr * 36 + nh2 * 8 + nw2];
                    }
                }
                zreg[r] = s;
            }
            __syncthreads();   // all reads of y done before overwrite
            #pragma unroll
            for (int r = 0; r < 12; ++r) {
                int rr = rg + 8 * r;
                qb[rr * 36 + nn] = zreg[r];
            }
        }
        __syncthreads();
        { // l2-normalize qc (rows 0..31) and kc (rows 32..63) over n
            const int row = t >> 2, q4 = t & 3;
            float s = 0.f;
            #pragma unroll
            for (int j = 0; j < 8; ++j) {
                float v = qb[row * 36 + q4 * 8 + j];
                s += v * v;
            }
            s += __shfl_xor(s, 1);
            s += __shfl_xor(s, 2);
            float inv = 1.0f / fmaxf(sqrtf(s), 1e-12f);
            #pragma unroll
            for (int j = 0; j < 8; ++j) qb[row * 36 + q4 * 8 + j] *= inv;
        }
        __syncthreads();
        { // attn_c = softmax(qc kc^T * temp + |i-j|*dlog)
            const int ci = t >> 3, mg = t & 7;
            const float temph = temperature[h];
            const float dlog = logf(1.0f - exp2f(-2.0f - (2.0f * (float)h) / 3.0f));
            float4 qrow[8];
            #pragma unroll
            for (int k4 = 0; k4 < 8; ++k4)
                qrow[k4] = *(const float4*)&qb[ci * 36 + k4 * 4];
            float pv[4];
            float mx = -1e30f;
            #pragma unroll
            for (int r = 0; r < 4; ++r) {
                int cj = mg + 8 * r;
                float s = 0.f;
                #pragma unroll
                for (int k4 = 0; k4 < 8; ++k4) {
                    float4 kv = *(const float4*)&qb[(32 + cj) * 36 + k4 * 4];
                    s += qrow[k4].x * kv.x + qrow[k4].y * kv.y
                       + qrow[k4].z * kv.z + qrow[k4].w * kv.w;
                }
                s = s * temph + fabsf((float)(ci - cj)) * dlog;
                pv[r] = s;
                mx = fmaxf(mx, s);
            }
            mx = fmaxf(mx, __shfl_xor(mx, 1));
            mx = fmaxf(mx, __shfl_xor(mx, 2));
            mx = fmaxf(mx, __shfl_xor(mx, 4));
            float sum = 0.f;
            #pragma unroll
            for (int r = 0; r < 4; ++r) { pv[r] = expf(pv[r] - mx); sum += pv[r]; }
            sum += __shfl_xor(sum, 1);
            sum += __shfl_xor(sum, 2);
            sum += __shfl_xor(sum, 4);
            float inv = 1.0f / sum;
            #pragma unroll
            for (int r = 0; r < 4; ++r) attnb[ci][mg + 8 * r] = pv[r] * inv;
        }
        __syncthreads();
        { // x2 = attn_c @ vc  -> ao[n][h*32+c] (token-major for projC GEMM)
            const int cc = t >> 3, ng = t & 7;
            float ox = 0, oy = 0, oz = 0, ow = 0;
            for (int d = 0; d < 32; ++d) {
                float a = attnb[cc][d];
                float4 vv = *(const float4*)&qb[(64 + d) * 36 + ng * 4];
                ox += a * vv.x; oy += a * vv.y; oz += a * vv.z; ow += a * vv.w;
            }
            ao[ng * 4 + 0][h * 32 + cc] = ox;
            ao[ng * 4 + 1][h * 32 + cc] = oy;
            ao[ng * 4 + 2][h * 32 + cc] = oz;
            ao[ng * 4 + 3][h * 32 + cc] = ow;
        }
        __syncthreads();
    }

    // ---- projC GEMM: acc2 ----
    float acc2[24];
    #pragma unroll
    for (int r = 0; r < 24; ++r) acc2[r] = projC_b[cq * 24 + r];
    for (int k4 = 0; k4 < 48; ++k4) {
        float4 xv = *(const float4*)&ao[np][k4 * 4];
        #pragma unroll
        for (int r = 0; r < 24; ++r) {
            float4 wv = *(const float4*)(projC_w + (cq * 24 + r) * CCH + k4 * 4);
            acc2[r] += xv.x * wv.x + xv.y * wv.y + xv.z * wv.z + xv.w * wv.w;
        }
    }

    // ---- out = x1 + x2 * (1 + attn_spatial[n]) ----
    float aspn = 1.0f + aspl[np];
    float* ob = out + (size_t)b * (NT * CCH) + np * CCH + cq * 24;
    #pragma unroll
    for (int u = 0; u < 6; ++u) {
        float4 o;
        o.x = acc1[4 * u + 0] + acc2[4 * u + 0] * aspn;
        o.y = acc1[4 * u + 1] + acc2[4 * u + 1] * aspn;
        o.z = acc1[4 * u + 2] + acc2[4 * u + 2] * aspn;
        o.w = acc1[4 * u + 3] + acc2[4 * u + 3] * aspn;
        *(float4*)(ob + 4 * u) = o;
    }
}

extern "C" void kernel_launch(void* const* d_in, const int* in_sizes, int n_in,
                              void* d_out, int out_size, void* d_ws, size_t ws_size,
                              hipStream_t stream) {
    (void)n_in; (void)out_size; (void)d_ws; (void)ws_size;
    const float* x         = (const float*)d_in[0];
    const float* qkv_w     = (const float*)d_in[1];
    const float* qkv_b     = (const float*)d_in[2];
    const float* proj_w    = (const float*)d_in[3];
    const float* proj_b    = (const float*)d_in[4];
    const float* rpb_table = (const float*)d_in[5];
    const float* temp      = (const float*)d_in[6];
    const float* qkvC_w    = (const float*)d_in[7];
    const float* dw_w      = (const float*)d_in[8];
    const float* projC_w   = (const float*)d_in[9];
    const float* projC_b   = (const float*)d_in[10];
    const float* gs_w1     = (const float*)d_in[11];
    const float* gs_b1     = (const float*)d_in[12];
    const float* bn_g      = (const float*)d_in[13];
    const float* bn_b      = (const float*)d_in[14];
    const float* bn_m      = (const float*)d_in[15];
    const float* bn_v      = (const float*)d_in[16];
    const float* gs_w2     = (const float*)d_in[17];
    const float* gs_b2     = (const float*)d_in[18];
    float* out = (float*)d_out;

    int B = in_sizes[0] / (NT * CCH);   // 4096
    vsa_kernel<<<B, 256, 0, stream>>>(x, qkv_w, qkv_b, proj_w, proj_b,
                                      rpb_table, temp, qkvC_w, dw_w,
                                      projC_w, projC_b, gs_w1, gs_b1,
                                      bn_g, bn_b, bn_m, bn_v, gs_w2, gs_b2,
                                      out);
}

// Round 2
// 668.351 us; speedup vs baseline: 10.9944x; 10.9944x over previous
//
#include <hip/hip_runtime.h>
#include <math.h>

typedef _Float16 f16;
typedef _Float16 f16x8 __attribute__((ext_vector_type(8)));
typedef _Float16 f16x4 __attribute__((ext_vector_type(4)));
typedef float    f32x4 __attribute__((ext_vector_type(4)));

#define MFMA16(A,B,C) __builtin_amdgcn_mfma_f32_16x16x32_f16(A,B,C,0,0,0)

#define QS   40            // qkv/P row stride in halfs (80 B: 16B-aligned, bank-clean)
#define HSZ  (32*QS)       // one 32x32 head matrix
#define OFFK (6*HSZ)
#define OFFV (12*HSZ)
#define AOS  216           // ao row stride in halfs (432 B: 16B-aligned, bank-clean)

// f16 weight cache offsets (in halfs) inside d_ws
#define W_QKV   0
#define W_QKVC  110592
#define W_PROJ  221184
#define W_PROJC 258048
#define W_TOTAL 294912

__global__ void cvt_weights(const float* __restrict__ a, const float* __restrict__ b,
                            const float* __restrict__ c, const float* __restrict__ d,
                            f16* __restrict__ ws)
{
    int i = blockIdx.x * 256 + threadIdx.x;
    if (i < 110592) {
        ws[W_QKV  + i] = (f16)a[i];
        ws[W_QKVC + i] = (f16)b[i];
    } else {
        int j = i - 110592;
        if (j < 36864) {
            ws[W_PROJ  + j] = (f16)c[j];
            ws[W_PROJC + j] = (f16)d[j];
        }
    }
}

template<bool W16>
__device__ __forceinline__ f16x8 ldw8(const void* base, int idx)
{
    if constexpr (W16) {
        return *(const f16x8*)((const f16*)base + idx);
    } else {
        const float* p = (const float*)base + idx;
        float4 u = *(const float4*)p;
        float4 v = *(const float4*)(p + 4);
        f16x8 r;
        r[0]=(f16)u.x; r[1]=(f16)u.y; r[2]=(f16)u.z; r[3]=(f16)u.w;
        r[4]=(f16)v.x; r[5]=(f16)v.y; r[6]=(f16)v.z; r[7]=(f16)v.w;
        return r;
    }
}

template<bool W16>
__global__ __launch_bounds__(256, 2)
void vsa_kernel(const float* __restrict__ x,
                const float* __restrict__ qkv_w, const float* __restrict__ qkv_b,
                const float* __restrict__ proj_w, const float* __restrict__ proj_b,
                const float* __restrict__ rpb_table, const float* __restrict__ temperature,
                const float* __restrict__ qkvC_w, const float* __restrict__ dw_w,
                const float* __restrict__ projC_w, const float* __restrict__ projC_b,
                const float* __restrict__ gs_w1, const float* __restrict__ gs_b1,
                const float* __restrict__ bn_g, const float* __restrict__ bn_b,
                const float* __restrict__ bn_m, const float* __restrict__ bn_v,
                const float* __restrict__ gs_w2, const float* __restrict__ gs_b2,
                const f16* __restrict__ ws, float* __restrict__ out)
{
    // LDS: 46080 + 13824 + 10240 + 2520 + 256 = 72920 B -> 2 blocks/CU
    __shared__ f16   sQKV[18*HSZ];       // branch1: Q[h][tok][d], K[h][tok][d], V[h][d][tok]
                                         // branch2 (reuse): Y[ch=0..575][tok]
    __shared__ f16   sAO[32*AOS];        // attn-out [tok][192ch], both branches
    __shared__ f16   sP[4*32*QS];        // per-wave P buffer [m][n]
    __shared__ float rl[630];            // rpb table
    __shared__ float y1n[32];
    __shared__ float aspl[32];           // 1 + attn_spatial[token]

    const int t    = threadIdx.x;
    const int w    = t >> 6;             // wave 0..3
    const int lane = t & 63;
    const int l15  = lane & 15;
    const int g    = lane >> 4;          // 0..3

    const float* xb = x + (size_t)blockIdx.x * 6144;
    const f32x4 z4 = {0.f, 0.f, 0.f, 0.f};

    // ---- stage rpb + gate stage 1 ----
    for (int i = t; i < 630; i += 256) rl[i] = rpb_table[i];
    if (t < 32) {
        // softmax rows sum to 1 -> pooled == 1/32 exactly; 3x3 conv on 1x1 -> center tap
        float y1 = gs_b1[t];
        #pragma unroll
        for (int hh = 0; hh < 6; ++hh) y1 += gs_w1[t*54 + hh*9 + 4] * (1.0f/32.0f);
        y1n[t] = (y1 - bn_m[t]) * rsqrtf(bn_v[t] + 1e-5f) * bn_g[t] + bn_b[t];
    }

    // ---- X as MFMA B-fragments in registers (used by GEMM1 and GEMM1C) ----
    f16x8 xf[6][2];
    #pragma unroll
    for (int kt = 0; kt < 6; ++kt)
        #pragma unroll
        for (int nt = 0; nt < 2; ++nt) {
            const float* p = xb + (nt*16 + l15)*192 + kt*32 + g*8;
            float4 u = *(const float4*)p;
            float4 v = *(const float4*)(p + 4);
            f16x8 r;
            r[0]=(f16)u.x; r[1]=(f16)u.y; r[2]=(f16)u.z; r[3]=(f16)u.w;
            r[4]=(f16)v.x; r[5]=(f16)v.y; r[6]=(f16)v.z; r[7]=(f16)v.w;
            xf[kt][nt] = r;
        }

    // ================= GEMM1: qkv^T = qkv_w @ x^T  (M=576 ch, N=32 tok, K=192) =======
    {
        const void* wb = W16 ? (const void*)ws : (const void*)qkv_w;
        f32x4 acc[9][2];
        #pragma unroll
        for (int mt = 0; mt < 9; ++mt) { acc[mt][0] = z4; acc[mt][1] = z4; }
        #pragma unroll
        for (int kt = 0; kt < 6; ++kt) {
            f16x8 af[9];
            #pragma unroll
            for (int mt = 0; mt < 9; ++mt)
                af[mt] = ldw8<W16>(wb, (144*w + 16*mt + l15)*192 + kt*32 + g*8);
            #pragma unroll
            for (int mt = 0; mt < 9; ++mt) {
                acc[mt][0] = MFMA16(af[mt], xf[kt][0], acc[mt][0]);
                acc[mt][1] = MFMA16(af[mt], xf[kt][1], acc[mt][1]);
            }
        }
        const float scale = 0.17677669529663687f;  // 32^-0.5
        #pragma unroll
        for (int mt = 0; mt < 9; ++mt) {
            int chb   = 144*w + 16*mt;          // tile base channel (wave-uniform)
            int which = chb / 192;              // 0=q 1=k 2=v
            int hh    = (chb % 192) >> 5;
            int db    = (chb & 31) + 4*g;       // d-base within head for this lane
            float4 bi = *(const float4*)(qkv_b + chb + 4*g);
            #pragma unroll
            for (int nt = 0; nt < 2; ++nt) {
                int token = 16*nt + l15;
                f32x4 a = acc[mt][nt];
                if (which == 0) {
                    f16x4 o;
                    o[0]=(f16)((a[0]+bi.x)*scale); o[1]=(f16)((a[1]+bi.y)*scale);
                    o[2]=(f16)((a[2]+bi.z)*scale); o[3]=(f16)((a[3]+bi.w)*scale);
                    *(f16x4*)(sQKV + hh*HSZ + token*QS + db) = o;
                } else if (which == 1) {
                    f16x4 o;
                    o[0]=(f16)(a[0]+bi.x); o[1]=(f16)(a[1]+bi.y);
                    o[2]=(f16)(a[2]+bi.z); o[3]=(f16)(a[3]+bi.w);
                    *(f16x4*)(sQKV + OFFK + hh*HSZ + token*QS + db) = o;
                } else {   // V stored transposed: [d][token]
                    sQKV[OFFV + hh*HSZ + (db+0)*QS + token] = (f16)(a[0]+bi.x);
                    sQKV[OFFV + hh*HSZ + (db+1)*QS + token] = (f16)(a[1]+bi.y);
                    sQKV[OFFV + hh*HSZ + (db+2)*QS + token] = (f16)(a[2]+bi.z);
                    sQKV[OFFV + hh*HSZ + (db+3)*QS + token] = (f16)(a[3]+bi.w);
                }
            }
        }
    }
    __syncthreads();   // bar1: sQKV, rl, y1n ready

    // gate stage 2 (read after bar2+)
    if (t < 32) {
        float y2 = gs_b2[t];
        #pragma unroll
        for (int c = 0; c < 32; ++c) y2 += gs_w2[t*288 + c*9 + 4] * y1n[c];
        aspl[t] = 1.0f + y2;
    }

    // ================= branch-1 attention: one head per wave =================
    #pragma unroll 1
    for (int hi = 0; hi < 2; ++hi) {
        int h = w + 4*hi;
        if (h < 6) {
            f16x8 qa[2], kb[2];
            #pragma unroll
            for (int mt = 0; mt < 2; ++mt)
                qa[mt] = *(const f16x8*)(sQKV + h*HSZ + (16*mt + l15)*QS + 8*g);
            #pragma unroll
            for (int nt = 0; nt < 2; ++nt)
                kb[nt] = *(const f16x8*)(sQKV + OFFK + h*HSZ + (16*nt + l15)*QS + 8*g);
            f32x4 s[2][2];
            #pragma unroll
            for (int mt = 0; mt < 2; ++mt)
                #pragma unroll
                for (int nt = 0; nt < 2; ++nt)
                    s[mt][nt] = MFMA16(qa[mt], kb[nt], z4);

            float pr[2][2][4];
            #pragma unroll
            for (int mt = 0; mt < 2; ++mt)
                #pragma unroll
                for (int nt = 0; nt < 2; ++nt)
                    #pragma unroll
                    for (int r = 0; r < 4; ++r) {
                        int m = 16*mt + 4*g + r, n = 16*nt + l15;
                        int dh = (m>>3) - (n>>3) + 3;
                        int dwd = (m&7) - (n&7) + 7;
                        pr[mt][nt][r] = s[mt][nt][r] + rl[(dh*15+dwd)*6 + h];
                    }
            #pragma unroll
            for (int mt = 0; mt < 2; ++mt)
                #pragma unroll
                for (int r = 0; r < 4; ++r) {
                    float mx = fmaxf(pr[mt][0][r], pr[mt][1][r]);
                    mx = fmaxf(mx, __shfl_xor(mx, 1));
                    mx = fmaxf(mx, __shfl_xor(mx, 2));
                    mx = fmaxf(mx, __shfl_xor(mx, 4));
                    mx = fmaxf(mx, __shfl_xor(mx, 8));
                    float e0 = __expf(pr[mt][0][r] - mx);
                    float e1 = __expf(pr[mt][1][r] - mx);
                    float sm = e0 + e1;
                    sm += __shfl_xor(sm, 1);
                    sm += __shfl_xor(sm, 2);
                    sm += __shfl_xor(sm, 4);
                    sm += __shfl_xor(sm, 8);
                    float inv = 1.0f / sm;
                    pr[mt][0][r] = e0*inv;
                    pr[mt][1][r] = e1*inv;
                }
            f16* Pw = sP + w*(32*QS);
            #pragma unroll
            for (int mt = 0; mt < 2; ++mt)
                #pragma unroll
                for (int nt = 0; nt < 2; ++nt)
                    #pragma unroll
                    for (int r = 0; r < 4; ++r)
                        Pw[(16*mt + 4*g + r)*QS + 16*nt + l15] = (f16)pr[mt][nt][r];

            // O^T = V^T @ P^T  (A = V[d][n], B[k=n][col=tok] = P[tok][n])
            f16x8 va[2], pb[2];
            #pragma unroll
            for (int mt = 0; mt < 2; ++mt)
                va[mt] = *(const f16x8*)(sQKV + OFFV + h*HSZ + (16*mt + l15)*QS + 8*g);
            #pragma unroll
            for (int nt = 0; nt < 2; ++nt)
                pb[nt] = *(const f16x8*)(Pw + (16*nt + l15)*QS + 8*g);
            #pragma unroll
            for (int mt = 0; mt < 2; ++mt)
                #pragma unroll
                for (int nt = 0; nt < 2; ++nt) {
                    f32x4 o = MFMA16(va[mt], pb[nt], z4);
                    int token = 16*nt + l15;
                    int dbv = 16*mt + 4*g;
                    f16x4 ov;
                    ov[0]=(f16)o[0]; ov[1]=(f16)o[1]; ov[2]=(f16)o[2]; ov[3]=(f16)o[3];
                    *(f16x4*)(sAO + token*AOS + h*32 + dbv) = ov;
                }
        }
    }
    __syncthreads();   // bar2: sAO (branch1) ready

    // ================= proj GEMM (M=32 tok, N=192, K=192), acc in regs =================
    f32x4 acc1[2][3];
    {
        const void* wb = W16 ? (const void*)(ws + W_PROJ) : (const void*)proj_w;
        #pragma unroll
        for (int ct = 0; ct < 3; ++ct) {
            float bi = proj_b[48*w + 16*ct + l15];
            f32x4 b4 = {bi, bi, bi, bi};
            acc1[0][ct] = b4; acc1[1][ct] = b4;
        }
        #pragma unroll
        for (int kt = 0; kt < 6; ++kt) {
            f16x8 aa[2], bb[3];
            #pragma unroll
            for (int mt = 0; mt < 2; ++mt)
                aa[mt] = *(const f16x8*)(sAO + (16*mt + l15)*AOS + kt*32 + 8*g);
            #pragma unroll
            for (int ct = 0; ct < 3; ++ct)
                bb[ct] = ldw8<W16>(wb, (48*w + 16*ct + l15)*192 + kt*32 + 8*g);
            #pragma unroll
            for (int mt = 0; mt < 2; ++mt)
                #pragma unroll
                for (int ct = 0; ct < 3; ++ct)
                    acc1[mt][ct] = MFMA16(aa[mt], bb[ct], acc1[mt][ct]);
        }
    }

    // ================= GEMM1C: y = qkvC_w @ x^T -> Y[ch][token] in sQKV ==============
    {
        const void* wb = W16 ? (const void*)(ws + W_QKVC) : (const void*)qkvC_w;
        f32x4 acc[9][2];
        #pragma unroll
        for (int mt = 0; mt < 9; ++mt) { acc[mt][0] = z4; acc[mt][1] = z4; }
        #pragma unroll
        for (int kt = 0; kt < 6; ++kt) {
            f16x8 af[9];
            #pragma unroll
            for (int mt = 0; mt < 9; ++mt)
                af[mt] = ldw8<W16>(wb, (144*w + 16*mt + l15)*192 + kt*32 + g*8);
            #pragma unroll
            for (int mt = 0; mt < 9; ++mt) {
                acc[mt][0] = MFMA16(af[mt], xf[kt][0], acc[mt][0]);
                acc[mt][1] = MFMA16(af[mt], xf[kt][1], acc[mt][1]);
            }
        }
        #pragma unroll
        for (int mt = 0; mt < 9; ++mt) {
            int chb = 144*w + 16*mt;
            #pragma unroll
            for (int nt = 0; nt < 2; ++nt) {
                int token = 16*nt + l15;
                f32x4 a = acc[mt][nt];
                sQKV[(chb + 4*g + 0)*QS + token] = (f16)a[0];
                sQKV[(chb + 4*g + 1)*QS + token] = (f16)a[1];
                sQKV[(chb + 4*g + 2)*QS + token] = (f16)a[2];
                sQKV[(chb + 4*g + 3)*QS + token] = (f16)a[3];
            }
        }
    }
    __syncthreads();   // bar3: Y ready

    // ================= branch-2 (MDTA): one head per wave ====================
    #pragma unroll 1
    for (int hi = 0; hi < 2; ++hi) {
        int h = w + 4*hi;
        if (h < 6) {
            f16x8 qa[2], kb[2], vb[2];
            // depthwise 3x3 -> l2norm -> q/k fragments (element: row=l15+16mt, n=8g+b)
            #pragma unroll
            for (int mt = 0; mt < 2; ++mt) {
                int d = 16*mt + l15;
                #pragma unroll
                for (int qk = 0; qk < 2; ++qk) {
                    int ch = qk*192 + h*32 + d;
                    float wr[9];
                    #pragma unroll
                    for (int i2 = 0; i2 < 9; ++i2) wr[i2] = dw_w[ch*9 + i2];
                    const f16* yr = sQKV + ch*QS;
                    float z[8], ss = 0.f;
                    #pragma unroll
                    for (int b2 = 0; b2 < 8; ++b2) {
                        float s2 = 0.f;
                        #pragma unroll
                        for (int dh2 = 0; dh2 < 3; ++dh2) {
                            int h2 = g + dh2 - 1;
                            if (h2 >= 0 && h2 < 4) {
                                #pragma unroll
                                for (int dw2 = 0; dw2 < 3; ++dw2) {
                                    int w2 = b2 + dw2 - 1;
                                    if (w2 >= 0 && w2 < 8)
                                        s2 += wr[dh2*3 + dw2] * (float)yr[h2*8 + w2];
                                }
                            }
                        }
                        z[b2] = s2; ss += s2*s2;
                    }
                    ss += __shfl_xor(ss, 16);
                    ss += __shfl_xor(ss, 32);
                    float inv = 1.0f / fmaxf(sqrtf(ss), 1e-12f);
                    if (qk == 0) {
                        #pragma unroll
                        for (int b2 = 0; b2 < 8; ++b2) qa[mt][b2] = (f16)(z[b2]*inv);
                    } else {
                        #pragma unroll
                        for (int b2 = 0; b2 < 8; ++b2) kb[mt][b2] = (f16)(z[b2]*inv);
                    }
                }
            }
            // vc fragments (element: d'=8g+b, n=l15+16nt)
            #pragma unroll
            for (int nt = 0; nt < 2; ++nt) {
                int n = 16*nt + l15;
                int nh = n >> 3, nw = n & 7;
                #pragma unroll
                for (int b2 = 0; b2 < 8; ++b2) {
                    int ch = 384 + h*32 + 8*g + b2;
                    const float* wp = dw_w + ch*9;
                    const f16* yr = sQKV + ch*QS;
                    float s2 = 0.f;
                    #pragma unroll
                    for (int dh2 = 0; dh2 < 3; ++dh2) {
                        int h2 = nh + dh2 - 1;
                        if (h2 >= 0 && h2 < 4) {
                            #pragma unroll
                            for (int dw2 = 0; dw2 < 3; ++dw2) {
                                int w2 = nw + dw2 - 1;
                                if (w2 >= 0 && w2 < 8)
                                    s2 += wp[dh2*3 + dw2] * (float)yr[h2*8 + w2];
                            }
                        }
                    }
                    vb[nt][b2] = (f16)s2;
                }
            }
            // S_c = qc kc^T * temp + |d-d'|*dlog ; softmax over d'
            float temph = temperature[h];
            float dlog  = logf(1.0f - exp2f(-2.0f - (2.0f*(float)h)/3.0f));
            f32x4 s[2][2];
            #pragma unroll
            for (int mt = 0; mt < 2; ++mt)
                #pragma unroll
                for (int nt = 0; nt < 2; ++nt)
                    s[mt][nt] = MFMA16(qa[mt], kb[nt], z4);
            float pr[2][2][4];
            #pragma unroll
            for (int mt = 0; mt < 2; ++mt)
                #pragma unroll
                for (int nt = 0; nt < 2; ++nt)
                    #pragma unroll
                    for (int r = 0; r < 4; ++r) {
                        int di = 16*mt + 4*g + r, dj = 16*nt + l15;
                        pr[mt][nt][r] = s[mt][nt][r]*temph + fabsf((float)(di - dj))*dlog;
                    }
            #pragma unroll
            for (int mt = 0; mt < 2; ++mt)
                #pragma unroll
                for (int r = 0; r < 4; ++r) {
                    float mx = fmaxf(pr[mt][0][r], pr[mt][1][r]);
                    mx = fmaxf(mx, __shfl_xor(mx, 1));
                    mx = fmaxf(mx, __shfl_xor(mx, 2));
                    mx = fmaxf(mx, __shfl_xor(mx, 4));
                    mx = fmaxf(mx, __shfl_xor(mx, 8));
                    float e0 = __expf(pr[mt][0][r] - mx);
                    float e1 = __expf(pr[mt][1][r] - mx);
                    float sm = e0 + e1;
                    sm += __shfl_xor(sm, 1);
                    sm += __shfl_xor(sm, 2);
                    sm += __shfl_xor(sm, 4);
                    sm += __shfl_xor(sm, 8);
                    float inv = 1.0f / sm;
                    pr[mt][0][r] = e0*inv;
                    pr[mt][1][r] = e1*inv;
                }
            f16* Pw = sP + w*(32*QS);
            #pragma unroll
            for (int mt = 0; mt < 2; ++mt)
                #pragma unroll
                for (int nt = 0; nt < 2; ++nt)
                    #pragma unroll
                    for (int r = 0; r < 4; ++r)
                        Pw[(16*mt + 4*g + r)*QS + 16*nt + l15] = (f16)pr[mt][nt][r];
            // x2pre[d][n] = P @ vc ; D: col=n, rows=d -> contiguous ao writes
            f16x8 pa[2];
            #pragma unroll
            for (int mt = 0; mt < 2; ++mt)
                pa[mt] = *(const f16x8*)(Pw + (16*mt + l15)*QS + 8*g);
            #pragma unroll
            for (int mt = 0; mt < 2; ++mt)
                #pragma unroll
                for (int nt = 0; nt < 2; ++nt) {
                    f32x4 o = MFMA16(pa[mt], vb[nt], z4);
                    int token = 16*nt + l15;
                    int dbv = 16*mt + 4*g;
                    f16x4 ov;
                    ov[0]=(f16)o[0]; ov[1]=(f16)o[1]; ov[2]=(f16)o[2]; ov[3]=(f16)o[3];
                    *(f16x4*)(sAO + token*AOS + h*32 + dbv) = ov;
                }
        }
    }
    __syncthreads();   // bar4: sAO (branch2) ready

    // ================= projC GEMM + gate + store =================
    f32x4 acc2[2][3];
    {
        const void* wb = W16 ? (const void*)(ws + W_PROJC) : (const void*)projC_w;
        #pragma unroll
        for (int ct = 0; ct < 3; ++ct) {
            float bi = projC_b[48*w + 16*ct + l15];
            f32x4 b4 = {bi, bi, bi, bi};
            acc2[0][ct] = b4; acc2[1][ct] = b4;
        }
        #pragma unroll
        for (int kt = 0; kt < 6; ++kt) {
            f16x8 aa[2], bb[3];
            #pragma unroll
            for (int mt = 0; mt < 2; ++mt)
                aa[mt] = *(const f16x8*)(sAO + (16*mt + l15)*AOS + kt*32 + 8*g);
            #pragma unroll
            for (int ct = 0; ct < 3; ++ct)
                bb[ct] = ldw8<W16>(wb, (48*w + 16*ct + l15)*192 + kt*32 + 8*g);
            #pragma unroll
            for (int mt = 0; mt < 2; ++mt)
                #pragma unroll
                for (int ct = 0; ct < 3; ++ct)
                    acc2[mt][ct] = MFMA16(aa[mt], bb[ct], acc2[mt][ct]);
        }
    }

    float* ob = out + (size_t)blockIdx.x * 6144;
    #pragma unroll
    for (int mt = 0; mt < 2; ++mt)
        #pragma unroll
        for (int r = 0; r < 4; ++r) {
            int m = 16*mt + 4*g + r;
            float asp = aspl[m];
            #pragma unroll
            for (int ct = 0; ct < 3; ++ct) {
                int c = 48*w + 16*ct + l15;
                ob[m*192 + c] = acc1[mt][ct][r] + acc2[mt][ct][r]*asp;
            }
        }
}

extern "C" void kernel_launch(void* const* d_in, const int* in_sizes, int n_in,
                              void* d_out, int out_size, void* d_ws, size_t ws_size,
                              hipStream_t stream) {
    (void)n_in; (void)out_size;
    const float* x         = (const float*)d_in[0];
    const float* qkv_w     = (const float*)d_in[1];
    const float* qkv_b     = (const float*)d_in[2];
    const float* proj_w    = (const float*)d_in[3];
    const float* proj_b    = (const float*)d_in[4];
    const float* rpb_table = (const float*)d_in[5];
    const float* temp      = (const float*)d_in[6];
    const float* qkvC_w    = (const float*)d_in[7];
    const float* dw_w      = (const float*)d_in[8];
    const float* projC_w   = (const float*)d_in[9];
    const float* projC_b   = (const float*)d_in[10];
    const float* gs_w1     = (const float*)d_in[11];
    const float* gs_b1     = (const float*)d_in[12];
    const float* bn_g      = (const float*)d_in[13];
    const float* bn_b      = (const float*)d_in[14];
    const float* bn_m      = (const float*)d_in[15];
    const float* bn_v      = (const float*)d_in[16];
    const float* gs_w2     = (const float*)d_in[17];
    const float* gs_b2     = (const float*)d_in[18];
    float* out = (float*)d_out;

    int B = in_sizes[0] / (32 * 192);   // 4096
    bool use_ws = (d_ws != nullptr) && (ws_size >= (size_t)W_TOTAL * sizeof(f16));
    if (use_ws) {
        cvt_weights<<<576, 256, 0, stream>>>(qkv_w, qkvC_w, proj_w, projC_w, (f16*)d_ws);
        vsa_kernel<true><<<B, 256, 0, stream>>>(x, qkv_w, qkv_b, proj_w, proj_b,
                                                rpb_table, temp, qkvC_w, dw_w,
                                                projC_w, projC_b, gs_w1, gs_b1,
                                                bn_g, bn_b, bn_m, bn_v, gs_w2, gs_b2,
                                                (const f16*)d_ws, out);
    } else {
        vsa_kernel<false><<<B, 256, 0, stream>>>(x, qkv_w, qkv_b, proj_w, proj_b,
                                                 rpb_table, temp, qkvC_w, dw_w,
                                                 projC_w, projC_b, gs_w1, gs_b1,
                                                 bn_g, bn_b, bn_m, bn_v, gs_w2, gs_b2,
                                                 nullptr, out);
    }
}